// Round 10
// baseline (209.890 us; speedup 1.0000x reference)
//
#include <hip/hip_runtime.h>
#include <math.h>

#define EPSF 1e-8f

typedef _Float16 f16x8 __attribute__((ext_vector_type(8)));
typedef float f32x4 __attribute__((ext_vector_type(4)));

#define GLOAD_LDS16(g, l)                                                      \
  __builtin_amdgcn_global_load_lds(                                            \
      (const __attribute__((address_space(1))) unsigned int*)(g),              \
      (__attribute__((address_space(3))) unsigned int*)(l), 16, 0, 0)

#define WAITV(n) asm volatile("s_waitcnt vmcnt(" #n ")" ::: "memory")
#define BAR() __builtin_amdgcn_s_barrier()
#define SBAR0() __builtin_amdgcn_sched_barrier(0)

__device__ __forceinline__ unsigned int ord_from_float(float f) {
  unsigned int u = __float_as_uint(f);
  return (u & 0x80000000u) ? ~u : (u | 0x80000000u);
}

__device__ __forceinline__ float float_from_ord(unsigned int o) {
  return (o & 0x80000000u) ? __uint_as_float(o & 0x7fffffffu)
                           : __uint_as_float(~o);
}

__device__ __forceinline__ unsigned long long shfl_xor_u64(unsigned long long x, int m) {
  int lo = __shfl_xor((int)(unsigned int)(x & 0xffffffffull), m, 64);
  int hi = __shfl_xor((int)(unsigned int)(x >> 32), m, 64);
  return ((unsigned long long)(unsigned int)hi << 32) | (unsigned int)lo;
}

// ---------------- fused prep kernels ----------------
__global__ __launch_bounds__(64) void prep_A_kernel(
    const float* __restrict__ inp, _Float16* __restrict__ Acat,
    float* __restrict__ s_in, unsigned long long* __restrict__ packed,
    int N, int D, int DP, int KPA) {
  int r = blockIdx.x;
  _Float16* row = Acat + (size_t)r * KPA;
  float s = 0.f;
  for (int d = threadIdx.x; d < DP; d += 64) {
    float lg = 0.f;
    if (r < N && d < D) {
      float x = inp[(size_t)r * D + d];
      s += x;
      lg = logf(x + EPSF);
    }
    _Float16 h = (_Float16)lg;
    _Float16 l = (_Float16)(lg - (float)h);
    row[d] = h;
    row[DP + d] = h;
    row[2 * DP + d] = l;
  }
  for (int d = threadIdx.x; d < KPA - 3 * DP; d += 64) row[3 * DP + d] = (_Float16)0.f;
  #pragma unroll
  for (int m = 1; m < 64; m <<= 1) s += __shfl_xor(s, m, 64);
  if (threadIdx.x == 0 && r < N) {
    s_in[r] = s;
    packed[r] = ~0ull;
  }
}

__global__ __launch_bounds__(64) void prep_B_kernel(
    const float* __restrict__ tgt, _Float16* __restrict__ Bcat,
    float* __restrict__ s_st, int M, int D, int DP, int KPA) {
  int r = blockIdx.x;
  _Float16* row = Bcat + (size_t)r * KPA;
  float s = 0.f;
  for (int d = threadIdx.x; d < DP; d += 64) {
    float x = 0.f;
    if (r < M && d < D) {
      x = tgt[(size_t)r * D + d];
      if (x > 1.0f)
        s += x * logf(x) - x + 0.5f * logf(6.283185307179586f * x);
    }
    _Float16 h = (_Float16)x;
    _Float16 l = (_Float16)(x - (float)h);
    row[d] = h;
    row[DP + d] = l;
    row[2 * DP + d] = h;
  }
  for (int d = threadIdx.x; d < KPA - 3 * DP; d += 64) row[3 * DP + d] = (_Float16)0.f;
  #pragma unroll
  for (int m = 1; m < 64; m <<= 1) s += __shfl_xor(s, m, 64);
  if (threadIdx.x == 0 && r < M) s_st[r] = s;
}

// ---------------- MFMA pair-min kernel: m201-style 4-phase/K-tile ----------------
// 256x256 tile, 8 waves (2Mx4N), BK=64, 2 LDS dbufs (128 KiB as 8 subunits of
// [256 rows][32 halves], round-3-verified swizzle). Per phase: {ds_read this
// phase's quadrant | stage 1 half-tile | sched_barrier | BAR | 16 MFMA
// (compiler's lgkm waits land after BAR -> cross-wave stagger) | BAR}.
// Counted vmcnt(2)@ph1 / vmcnt(4)@ph4; 1-4 half-tiles always in flight.
#define BT 256
#define SUBH 8192  // halves per subunit: 256 rows x 32 halves = 16 KB
#define SUB(d_, o_, k_) (((((d_) << 1) | (o_)) << 1) | (k_))

__global__ __launch_bounds__(512, 2) void mfma_pair_min_kernel(
    const _Float16* __restrict__ Acat, const _Float16* __restrict__ Bcat,
    const float* __restrict__ s_st, unsigned long long* __restrict__ packed,
    int N, int M, int KPA, int gx) {
  extern __shared__ __align__(16) _Float16 smem[];  // 8 * SUBH = 128 KiB
  const int t = threadIdx.x;
  const int lane = t & 63;
  const int wid = t >> 6;   // 0..7
  const int wr = wid >> 2;  // 0..1 -> 128 output rows
  const int wc = wid & 3;   // 0..3 -> 64 output cols

  // XCD chunking + column-major traversal inside each chunk (round-6 verified)
  const int nwg = gridDim.x;
  const int q8 = nwg >> 3;
  const int xcd = blockIdx.x & 7;
  const int i8 = blockIdx.x >> 3;
  int brow, bcol;
  if (q8 % gx == 0) {
    int bh = q8 / gx;
    brow = xcd * bh + i8 % bh;
    bcol = i8 / bh;
  } else {
    int wg = xcd * q8 + i8;
    brow = wg / gx;
    bcol = wg % gx;
  }
  const int row0 = brow * BT;
  const int col0 = bcol * BT;

  // Staging: wave wid owns rows [H*128 + wid*16, +16) for both k-halves
  // (2 gload_lds per thread per half-tile). LDS dest linear; global source
  // slot pre-swizzled: LDS(r,s) = global(r, s^((r>>1)&3)) (verified r3-r9).
  const int srow = lane >> 2;
  const int gs = (lane & 3) ^ ((lane >> 3) & 3);
  const _Float16* const aSt = Acat + (size_t)(row0 + wid * 16 + srow) * KPA + gs * 8;
  const _Float16* const bSt = Bcat + (size_t)(col0 + wid * 16 + srow) * KPA + gs * 8;

  // STG(dbuf, op, half, ktile): stage half-tile (rows H*128..+127, both
  // k-halves) of tile KT into dbuf. 2 gload_lds per thread.
#define STG(DD_, O_, H_, KT_)                                                  \
  do {                                                                         \
    const _Float16* gb_ = ((O_) ? bSt : aSt) + (size_t)(H_) * 128 * KPA +      \
                          (size_t)(KT_) * 64;                                  \
    _Float16* lb_ = smem + ((H_) * 128 + wid * 16) * 32;                       \
    GLOAD_LDS16(gb_, lb_ + SUB(DD_, O_, 0) * SUBH);                            \
    GLOAD_LDS16(gb_ + 32, lb_ + SUB(DD_, O_, 1) * SUBH);                       \
  } while (0)

  const int rl = lane & 15;
  const int qq = lane >> 4;
  const int sa = qq ^ ((rl >> 1) & 3);  // swizzled k-slot (row-base-independent)

  // A quadrant-set: 8 ds_read_b128 (4 row-frags x 2 k-halves)
#define LDA(SET_, D_, QR_)                                                     \
  do {                                                                         \
    _Pragma("unroll") for (int mm = 0; mm < 4; ++mm)                           \
      _Pragma("unroll") for (int kh = 0; kh < 2; ++kh)                         \
        SET_[mm][kh] = *(const f16x8*)(smem + SUB(D_, 0, kh) * SUBH +          \
            (wr * 128 + (QR_) * 64 + mm * 16 + rl) * 32 + sa * 8);             \
  } while (0)

  // B quadrant-set: 4 ds_read_b128 (2 col-frags x 2 k-halves)
#define LDB(SET_, D_, QC_)                                                     \
  do {                                                                         \
    _Pragma("unroll") for (int nn = 0; nn < 2; ++nn)                           \
      _Pragma("unroll") for (int kh = 0; kh < 2; ++kh)                         \
        SET_[nn][kh] = *(const f16x8*)(smem + SUB(D_, 1, kh) * SUBH +          \
            (wc * 64 + (QC_) * 32 + nn * 16 + rl) * 32 + sa * 8);              \
  } while (0)

  f32x4 acc[8][4] = {};
  f16x8 Aq0[4][2], Aq1[4][2], Bq0[2][2], Bq1[2][2];

#define MMQ(A_, B_, QR_, QC_)                                                  \
  do {                                                                         \
    __builtin_amdgcn_s_setprio(1);                                             \
    _Pragma("unroll") for (int mm = 0; mm < 4; ++mm)                           \
      _Pragma("unroll") for (int nn = 0; nn < 2; ++nn)                         \
        _Pragma("unroll") for (int kh = 0; kh < 2; ++kh)                       \
          acc[(QR_) * 4 + mm][(QC_) * 2 + nn] =                                \
              __builtin_amdgcn_mfma_f32_16x16x32_f16(                          \
                  A_[mm][kh], B_[nn][kh], acc[(QR_) * 4 + mm][(QC_) * 2 + nn], \
                  0, 0, 0);                                                    \
    __builtin_amdgcn_s_setprio(0);                                             \
  } while (0)

  const int NTILE = KPA >> 6;  // 9 for D=180

  // ---- prologue: tile0 fully + tile1 A-H0 (10 loads); wait all but A1H0 ----
  STG(0, 0, 0, 0); STG(0, 0, 1, 0); STG(0, 1, 0, 0); STG(0, 1, 1, 0);
  STG(1, 0, 0, 1);
  WAITV(2);
  BAR();
  LDA(Aq0, 0, 0);  // tile0 A(qr0); compiler lgkm-waits before first MFMA use

  for (int T = 0; T < NTILE; ++T) {
    const int d = T & 1, nd = d ^ 1;
    const bool last = (T == NTILE - 1);
    // ph1: B(qc0) | stage A(T+1)H1 | quad(0,0)
    // steady outstanding before wait: {B(T)H0, B(T)H1, A(T+1)H0} = 6
    if (last) { WAITV(0); } else { WAITV(2); }  // lands B(T) halves
    LDB(Bq0, d, 0);
    if (!last) STG(nd, 0, 1, T + 1);
    SBAR0();
    BAR();
    MMQ(Aq0, Bq0, 0, 0);
    BAR();
    // ph2: B(qc1) | stage B(T+1)H0 | quad(0,1)
    LDB(Bq1, d, 1);
    if (!last) STG(nd, 1, 0, T + 1);
    SBAR0();
    BAR();
    MMQ(Aq0, Bq1, 0, 1);
    BAR();
    // ph3: A(qr1) | stage B(T+1)H1 | quad(1,1)
    LDA(Aq1, d, 1);
    if (!last) STG(nd, 1, 1, T + 1);
    SBAR0();
    BAR();
    MMQ(Aq1, Bq1, 1, 1);
    BAR();
    // ph4: A(T+1)(qr0) | stage A(T+2)H0 | quad(1,0)
    // outstanding before wait: {A(T+1)H0,H1, B(T+1)H0,H1} = 8 -> lands A(T+1)
    if (!last) {
      WAITV(4);
      LDA(Aq0, nd, 0);                       // next tile's A(qr0): H0+H1 landed
      if (T < NTILE - 2) STG(d, 0, 0, T + 2);  // dbuf d: its A last read ph3 (safe)
    }
    SBAR0();
    BAR();
    MMQ(Aq1, Bq0, 1, 0);
    BAR();
  }

#undef STG
#undef LDA
#undef LDB
#undef MMQ

  // ---- fused min/argmin epilogue ----
  // C/D frag: col = lane&15, row = (lane>>4)*4 + reg   [guide §3, m89-verified]
  float stv[4];
  #pragma unroll
  for (int n = 0; n < 4; ++n) {
    int gj = col0 + wc * 64 + n * 16 + rl;
    stv[n] = (gj < M) ? s_st[gj] : __builtin_inff();
  }
  #pragma unroll
  for (int m = 0; m < 8; ++m) {
    #pragma unroll
    for (int g = 0; g < 4; ++g) {
      int grow = row0 + wr * 128 + m * 16 + qq * 4 + g;
      unsigned long long bst = ~0ull;
      #pragma unroll
      for (int n = 0; n < 4; ++n) {
        int gj = col0 + wc * 64 + n * 16 + rl;
        float val = stv[n] - acc[m][n][g];
        unsigned long long p =
            ((unsigned long long)ord_from_float(val) << 32) | (unsigned int)gj;
        if (p < bst) bst = p;
      }
      #pragma unroll
      for (int mm = 1; mm < 16; mm <<= 1) {
        unsigned long long o = shfl_xor_u64(bst, mm);
        if (o < bst) bst = o;
      }
      if (rl == 0 && grow < N) atomicMin(&packed[grow], bst);
    }
  }
}

// ---------------- finalize ----------------

__global__ __launch_bounds__(256) void finalize_kernel(
    const unsigned long long* __restrict__ packed,
    const float* __restrict__ s_in, float* __restrict__ out, int N) {
  __shared__ double sh[256];
  double s = 0.0;
  for (int i = threadIdx.x; i < N; i += 256) {
    unsigned long long p = packed[i];
    float val = float_from_ord((unsigned int)(p >> 32));
    out[1 + i] = (float)(unsigned int)(p & 0xffffffffull);
    s += (double)(s_in[i] + val);
  }
  sh[threadIdx.x] = s;
  __syncthreads();
  for (int off = 128; off > 0; off >>= 1) {
    if (threadIdx.x < off) sh[threadIdx.x] += sh[threadIdx.x + off];
    __syncthreads();
  }
  if (threadIdx.x == 0) out[0] = (float)(sh[0] / N);
}

extern "C" void kernel_launch(void* const* d_in, const int* in_sizes, int n_in,
                              void* d_out, int out_size, void* d_ws, size_t ws_size,
                              hipStream_t stream) {
  const float* inp = (const float*)d_in[0];
  const float* tgt = (const float*)d_in[1];
  float* out = (float*)d_out;

  int N = out_size - 1;  // outputs: [loss scalar, match[N]]
  int D = in_sizes[0] / N;
  int M = in_sizes[1] / D;

  int Npad = ((N + BT - 1) / BT) * BT;
  int Mpad = ((M + BT - 1) / BT) * BT;
  int DP = ((D + 31) / 32) * 32;
  int KPA = ((3 * DP + 63) / 64) * 64;  // 576 for D=180 -> 9 K-tiles of 64

  char* ws = (char*)d_ws;
  size_t off = 0;
  float* s_in = (float*)(ws + off); off += (size_t)N * 4;
  float* s_st = (float*)(ws + off); off += (size_t)M * 4;
  off = (off + 15) & ~(size_t)15;
  unsigned long long* packed = (unsigned long long*)(ws + off); off += (size_t)N * 8;
  off = (off + 15) & ~(size_t)15;
  _Float16* Acat = (_Float16*)(ws + off); off += (size_t)Npad * KPA * 2;
  _Float16* Bcat = (_Float16*)(ws + off); off += (size_t)Mpad * KPA * 2;

  prep_A_kernel<<<Npad, 64, 0, stream>>>(inp, Acat, s_in, packed, N, D, DP, KPA);
  prep_B_kernel<<<Mpad, 64, 0, stream>>>(tgt, Bcat, s_st, M, D, DP, KPA);

  const int ldsBytes = 8 * SUBH * 2;  // 128 KiB
  hipFuncSetAttribute((const void*)mfma_pair_min_kernel,
                      hipFuncAttributeMaxDynamicSharedMemorySize, ldsBytes);

  int gx = Mpad / BT, gy = Npad / BT;
  mfma_pair_min_kernel<<<gx * gy, 512, ldsBytes, stream>>>(Acat, Bcat, s_st,
                                                           packed, N, M, KPA, gx);

  finalize_kernel<<<1, 256, 0, stream>>>(packed, s_in, out, N);
}